// Round 6
// baseline (135.503 us; speedup 1.0000x reference)
//
#include <hip/hip_runtime.h>
#include <math.h>

#define TPB 256                    // dense-phase kernels block size
#define TPBP 512                   // pool kernel block size (2 co-resident blocks/CU)
#define FSCALE 16384.0f            // 2^14 fixed-point for fx/fy
#define INV_FSCALE (1.0f / 16384.0f)
#define FBIAS (1 << 17)            // per-add bias keeps packed fields positive
#define FCLAMP 7.0f                // |fx| clamp: 7*2^14 + 2^17 = 245760; *16384 < 2^32

// Round-5: pool to 2 co-resident blocks/CU (chunks 16->32, 512 blocks x 512 thr,
// launch_bounds(512,4)). With 1 block/CU the init->atomic-loop->writeout phases
// serialize per CU and loads/atomics of a single block contend with nothing to
// fill idle pipe slots (round-0's wave-count change was null -> not TLP-bound).
// Two independent blocks overlap A's atomic bursts with B's loads. Bin sums are
// fixed-point integers (exact, associative) -> re-chunking only reorders exact
// fp32 chunk-partials in k_layer1 (last-ulp, absmax dominated by 2^-14 quant).

// -------------------- pool: LDS int bins, 2 u64 atomics/pixel --------------------
__global__ __launch_bounds__(TPBP, 4)
void pool_kernel(const int* __restrict__ labels,
                 const float* __restrict__ fx,
                 const float* __restrict__ fy,
                 float* __restrict__ partial,
                 int K, int H, int W, int wlog, int chunks) {
    extern __shared__ unsigned long long sh[];   // geo[K] | fxy[K]
    unsigned long long* geo = sh;
    unsigned long long* fxy = sh + K;
    const int tid = threadIdx.x;

    for (int i = tid; i < K; i += TPBP) { geo[i] = 0ull; fxy[i] = 0ull; }
    __syncthreads();

    const int P = H * W;
    const int b = blockIdx.x / chunks;
    const int chunk = blockIdx.x - b * chunks;
    const int chunkP = P / chunks;
    const size_t base = (size_t)b * P + (size_t)chunk * chunkP;
    const int4*   l4p  = (const int4*)(labels + base);
    const float4* fx4p = (const float4*)(fx + base);
    const float4* fy4p = (const float4*)(fy + base);
    const int nvec = chunkP >> 2;

    for (int v = tid; v < nvec; v += TPBP) {
        int4   l4 = l4p[v];
        float4 f4 = fx4p[v];
        float4 g4 = fy4p[v];
        int p0 = chunk * chunkP + (v << 2);
        int   ls[4] = {l4.x, l4.y, l4.z, l4.w};
        float fs[4] = {f4.x, f4.y, f4.z, f4.w};
        float gs[4] = {g4.x, g4.y, g4.z, g4.w};
        #pragma unroll
        for (int s = 0; s < 4; ++s) {
            int p = p0 + s;
            int i, j;
            if (wlog >= 0) { i = p >> wlog; j = p & (W - 1); }
            else           { i = p / W;     j = p - i * W; }
            unsigned long long gadd = ((unsigned long long)i << 40)
                                    | ((unsigned long long)j << 16) | 1ull;
            int qx = __float2int_rn(fminf(fmaxf(fs[s], -FCLAMP), FCLAMP) * FSCALE) + FBIAS;
            int qy = __float2int_rn(fminf(fmaxf(gs[s], -FCLAMP), FCLAMP) * FSCALE) + FBIAS;
            unsigned long long fadd = ((unsigned long long)(unsigned int)qx << 32)
                                    | (unsigned long long)(unsigned int)qy;
            atomicAdd(&geo[ls[s]], gadd);
            atomicAdd(&fxy[ls[s]], fadd);
        }
    }
    __syncthreads();

    const float sx = 2.f / (float)(H - 1);           // xx varies along dim 2 (i)
    const float sy = 2.f / (float)(W - 1);           // yy varies along dim 3 (j)
    float* outp = partial + (size_t)blockIdx.x * K * 5;   // plane-major [f][K]
    for (int k = tid; k < K; k += TPBP) {
        unsigned long long g = geo[k];
        unsigned long long ff = fxy[k];
        unsigned int ci = (unsigned int)(g & 0xFFFFull);
        float cnt = (float)ci;
        float sj  = (float)(unsigned int)((g >> 16) & 0xFFFFFFull);
        float si  = (float)(unsigned int)(g >> 40);
        long long cbias = (long long)ci << 17;
        outp[0 * K + k] = (float)((long long)(ff >> 32) - cbias) * INV_FSCALE;
        outp[1 * K + k] = (float)((long long)(ff & 0xFFFFFFFFull) - cbias) * INV_FSCALE;
        outp[2 * K + k] = sx * si - cnt;             // sum xx
        outp[3 * K + k] = sy * sj - cnt;             // sum yy
        outp[4 * K + k] = cnt;                       // count
    }
}

// Unrolled strided accumulate: ROWS compile-time -> all loads in flight.
template <int ROWS>
__device__ __forceinline__ float red_fixed(const float* __restrict__ base, int stride) {
    float a = 0.f;
    #pragma unroll
    for (int r = 0; r < ROWS; ++r) a += base[(size_t)r * stride];
    return a;
}
__device__ __forceinline__ float red_dyn(const float* __restrict__ base, int rows, int stride) {
    float a = 0.f;
    #pragma unroll 8
    for (int r = 0; r < rows; ++r) a += base[(size_t)r * stride];
    return a;
}

// -------------------- K2: slab reduce -> feat + layer1 -> h1g + bn1 partials -----
__global__ __launch_bounds__(TPB)
void k_layer1(const float* __restrict__ partial,
              const int* __restrict__ frame_idx,
              const int* __restrict__ n_frames_p,
              const float* __restrict__ conv_w,
              const float* __restrict__ conv_b,
              float* __restrict__ statA,   // [nblk][128]: 64 sum | 64 sumsq
              float* __restrict__ h1g,     // [64][N]
              int K, int N, int chunks) {
    __shared__ float red[320];                       // [f][64]
    __shared__ float cw[320], cb[64];
    __shared__ float h1t[64 * 65];                   // [c][tt], pad 65 for col reads
    __shared__ float ps[256], pq[256];

    const int tid = threadIdx.x;
    const int bid = blockIdx.x;

    for (int i = tid; i < 320; i += TPB) cw[i] = conv_w[i];
    if (tid < 64) cb[tid] = conv_b[tid];

    const int t0 = bid * 64;
    const int b  = t0 / K;                           // 64 | K -> one batch per block
    const int k0 = t0 - b * K;

    // plane-major reads: wave f1 reads plane f1, fully coalesced
    const int f1 = tid >> 6, kk = tid & 63;
    float a0 = 0.f, a1 = 0.f;
    const float* pb = partial + (size_t)b * chunks * K * 5;
    if (chunks == 32) {
        #pragma unroll
        for (int ch = 0; ch < 32; ++ch) {
            const float* pc = pb + (size_t)ch * K * 5;
            a0 += pc[(size_t)f1 * K + k0 + kk];
            if (tid < 64) a1 += pc[(size_t)4 * K + k0 + tid];
        }
    } else if (chunks == 16) {
        #pragma unroll
        for (int ch = 0; ch < 16; ++ch) {
            const float* pc = pb + (size_t)ch * K * 5;
            a0 += pc[(size_t)f1 * K + k0 + kk];
            if (tid < 64) a1 += pc[(size_t)4 * K + k0 + tid];
        }
    } else {
        #pragma unroll 4
        for (int ch = 0; ch < chunks; ++ch) {
            const float* pc = pb + (size_t)ch * K * 5;
            a0 += pc[(size_t)f1 * K + k0 + kk];
            if (tid < 64) a1 += pc[(size_t)4 * K + k0 + tid];
        }
    }
    red[f1 * 64 + kk] = a0;
    if (tid < 64) red[4 * 64 + tid] = a1;
    __syncthreads();

    const int g  = tid >> 6;
    const int tt = tid & 63;
    const int t  = t0 + tt;
    const bool valid = t < N;

    const float cntv = red[4 * 64 + tt];
    const float inv  = 1.f / fmaxf(cntv, 1.f);
    const float invnf = 1.f / (float)(n_frames_p[0] - 1);
    const float x0 = valid ? (float)frame_idx[b] * invnf : 0.f;
    const float x1 = red[0 * 64 + tt] * inv;
    const float x2 = red[1 * 64 + tt] * inv;
    const float x3 = red[2 * 64 + tt] * inv;
    const float x4 = red[3 * 64 + tt] * inv;

    const int c0 = g * 16;
    #pragma unroll
    for (int j = 0; j < 16; ++j) {
        int c = c0 + j;
        const float* w = cw + c * 5;
        float h = cb[c] + w[0]*x0 + w[1]*x1 + w[2]*x2 + w[3]*x3 + w[4]*x4;
        h1g[(size_t)c * N + t] = h;                  // lane-coalesced dword store
        h1t[c * 65 + tt] = valid ? h : 0.f;          // masked copy for stats
    }
    __syncthreads();

    // transpose stat reduce: thread (cc, rr) sums 16 tokens of channel cc
    {
        const int cc = tid & 63, rr = tid >> 6;      // rr = 0..3
        float s = 0.f, q = 0.f;
        #pragma unroll
        for (int i = 0; i < 16; ++i) {               // bank = (cc+16rr+i)%32: free
            float v = h1t[cc * 65 + rr * 16 + i];
            s += v; q += v * v;
        }
        ps[rr * 64 + cc] = s;
        pq[rr * 64 + cc] = q;
    }
    __syncthreads();
    if (tid < 64) {
        float su = ps[tid] + ps[64 + tid] + ps[128 + tid] + ps[192 + tid];
        float sq = pq[tid] + pq[64 + tid] + pq[128 + tid] + pq[192 + tid];
        statA[(size_t)bid * 128 + tid] = su;         // plain stores: zero contention
        statA[(size_t)bid * 128 + 64 + tid] = sq;
    }
}

// -------------------- K3: statA reduce -> bn1 fold + layer2 -> h2g + bn2 partials
__global__ __launch_bounds__(TPB)
void k_layer2(const float* __restrict__ statA,
              const float* __restrict__ bn1_g,
              const float* __restrict__ bn1_b,
              const float* __restrict__ lin_w,
              const float* __restrict__ lin_b,
              const float* __restrict__ h1g,    // [64][N]
              float* __restrict__ statB,        // [nblk][64]: 32 sum | 32 sumsq
              float* __restrict__ h2g,          // [32][N]
              int N) {
    __shared__ float red[256], w2[2048], lb[32];
    __shared__ float sc1[64], sh1[64];
    __shared__ float h1t[64 * 64];                   // [c][tt] staged tile
    __shared__ float h2t[32 * 65];                   // [o][tt], pad 65 for col reads
    __shared__ float ps[256], pq[256];

    const int tid = threadIdx.x;
    const int bid = blockIdx.x;
    const int nblk = gridDim.x;
    const int t0 = bid * 64;

    for (int i = tid; i < 2048; i += TPB) w2[i] = lin_w[i];
    if (tid < 32) lb[tid] = lin_b[tid];

    // redundant statA reduce: compile-time trip count, all loads in flight
    {
        const int col  = tid & 127;                  // 0..63 sums, 64..127 sumsq
        const int half = tid >> 7;
        const int rows = nblk >> 1;
        const float* base = statA + (size_t)half * rows * 128 + col;
        red[tid] = (rows == 128) ? red_fixed<128>(base, 128)
                                 : red_dyn(base, rows, 128);
    }

    // stage h1 tile [64c][64t] -> LDS (overlaps the reduce's tail)
    {
        #pragma unroll
        for (int pass = 0; pass < 4; ++pass) {
            int idx = pass * TPB + tid;              // 0..1023 float4s
            int c = idx >> 4, q = idx & 15;
            float4 v = *(const float4*)(h1g + (size_t)c * N + t0 + q * 4);
            *(float4*)(&h1t[c * 64 + q * 4]) = v;
        }
    }
    __syncthreads();

    if (tid < 64) {
        float su = red[tid] + red[128 + tid];
        float sq = red[64 + tid] + red[192 + tid];
        float invN = 1.f / (float)N;
        float mean = su * invN;
        float var  = sq * invN - mean * mean;
        float s = bn1_g[tid] * rsqrtf(var + 1e-5f);
        sc1[tid] = s;
        sh1[tid] = bn1_b[tid] - mean * s;
    }
    __syncthreads();

    const int g  = tid >> 6;
    const int tt = tid & 63;
    const int t  = t0 + tt;
    const bool valid = t < N;

    float y[64];
    #pragma unroll
    for (int c = 0; c < 64; ++c)
        y[c] = fmaxf(h1t[c * 64 + tt] * sc1[c] + sh1[c], 0.f);

    const int o0 = g * 8;
    #pragma unroll
    for (int j = 0; j < 8; ++j) {
        int o = o0 + j;
        const float* wo = w2 + o * 64;
        float acc = lb[o];
        #pragma unroll
        for (int c = 0; c < 64; ++c) acc += wo[c] * y[c];
        h2g[(size_t)o * N + t] = acc;                // lane-coalesced dword store
        h2t[o * 65 + tt] = valid ? acc : 0.f;        // masked copy for stats
    }
    __syncthreads();

    // transpose stat reduce: thread (o, rr) sums 8 tokens of channel o
    {
        const int o = tid & 31, rr = tid >> 5;       // rr = 0..7
        float s = 0.f, q = 0.f;
        #pragma unroll
        for (int i = 0; i < 8; ++i) {                // bank = (o+8rr+i)%32: free
            float v = h2t[o * 65 + rr * 8 + i];
            s += v; q += v * v;
        }
        ps[rr * 32 + o] = s;
        pq[rr * 32 + o] = q;
    }
    __syncthreads();
    if (tid < 32) {
        float su = 0.f, sq = 0.f;
        #pragma unroll
        for (int rr = 0; rr < 8; ++rr) { su += ps[rr * 32 + tid]; sq += pq[rr * 32 + tid]; }
        statB[(size_t)bid * 64 + tid] = su;
        statB[(size_t)bid * 64 + 32 + tid] = sq;
    }
}

// -------------------- K4: statB reduce -> bn2 fold + normalize + store -----------
__global__ __launch_bounds__(TPB)
void k_final(const float* __restrict__ statB,
             const float* __restrict__ bn2_g,
             const float* __restrict__ bn2_b,
             const float* __restrict__ h2g,     // [32][N]
             float* __restrict__ out,
             int N) {
    __shared__ float red[256];
    __shared__ float sc2[32], sh2[32];
    __shared__ float h2t[32 * 68];                   // [o][tt], 16B-aligned rows
    __shared__ float ssqp[4 * 64], linv[64];

    const int tid = threadIdx.x;
    const int bid = blockIdx.x;
    const int nblk = gridDim.x;
    const int t0 = bid * 64;

    // redundant statB reduce: compile-time trip count
    {
        const int col = tid & 63;                    // 0..31 sums, 32..63 sumsq
        const int qr  = tid >> 6;
        const int rows = nblk >> 2;
        const float* base = statB + (size_t)qr * rows * 64 + col;
        red[tid] = (rows == 64) ? red_fixed<64>(base, 64)
                                : red_dyn(base, rows, 64);
    }

    // stage h2 tile [32o][64t] -> LDS
    {
        #pragma unroll
        for (int pass = 0; pass < 2; ++pass) {
            int idx = pass * TPB + tid;              // 0..511 float4s
            int o = idx >> 4, q = idx & 15;
            float4 v = *(const float4*)(h2g + (size_t)o * N + t0 + q * 4);
            *(float4*)(&h2t[o * 68 + q * 4]) = v;
        }
    }
    __syncthreads();

    if (tid < 32) {
        float su = red[tid] + red[64 + tid] + red[128 + tid] + red[192 + tid];
        float sq = red[32 + tid] + red[96 + tid] + red[160 + tid] + red[224 + tid];
        float invN = 1.f / (float)N;
        float mean = su * invN;
        float var  = sq * invN - mean * mean;
        float s = bn2_g[tid] * rsqrtf(var + 1e-5f);
        sc2[tid] = s;
        sh2[tid] = bn2_b[tid] - mean * s;
    }
    __syncthreads();

    const int g  = tid >> 6;
    const int tt = tid & 63;
    {
        const int o0 = g * 8;
        float ss = 0.f;
        #pragma unroll
        for (int j = 0; j < 8; ++j) {
            int o = o0 + j;
            float v = fmaxf(h2t[o * 68 + tt] * sc2[o] + sh2[o], 0.f);
            h2t[o * 68 + tt] = v;
            ss += v * v;
        }
        ssqp[g * 64 + tt] = ss;
    }
    __syncthreads();
    if (g == 0) {
        float tot = ssqp[tt] + ssqp[64 + tt] + ssqp[128 + tt] + ssqp[192 + tt];
        linv[tt] = 1.f / fmaxf(sqrtf(tot), 1e-8f);
    }
    __syncthreads();

    const int nq = min(512, (N - t0) * 8);           // float4s this block owns
    float4* o4 = (float4*)(out + (size_t)t0 * 32);
    for (int q = tid; q < nq; q += TPB) {
        int tk = q >> 3;
        int oo = (q & 7) * 4;
        float iv = linv[tk];
        o4[q] = make_float4(h2t[(oo + 0) * 68 + tk] * iv,
                            h2t[(oo + 1) * 68 + tk] * iv,
                            h2t[(oo + 2) * 68 + tk] * iv,
                            h2t[(oo + 3) * 68 + tk] * iv);
    }
}

extern "C" void kernel_launch(void* const* d_in, const int* in_sizes, int n_in,
                              void* d_out, int out_size, void* d_ws, size_t ws_size,
                              hipStream_t stream) {
    const int*   labels     = (const int*)d_in[0];
    const float* fx         = (const float*)d_in[1];
    const float* fy         = (const float*)d_in[2];
    const int*   frame_idx  = (const int*)d_in[3];
    const int*   n_frames_p = (const int*)d_in[4];
    // d_in[5] = n_labels (derived from out_size instead)
    const float* conv_w = (const float*)d_in[6];
    const float* conv_b = (const float*)d_in[7];
    const float* bn1_g  = (const float*)d_in[8];
    const float* bn1_b  = (const float*)d_in[9];
    const float* lin_w  = (const float*)d_in[10];
    const float* lin_b  = (const float*)d_in[11];
    const float* bn2_g  = (const float*)d_in[12];
    const float* bn2_b  = (const float*)d_in[13];
    float* out = (float*)d_out;

    const int B = in_sizes[3];                       // 16
    const int P = in_sizes[0] / B;                   // 262144
    const int W = (int)(sqrt((double)P) + 0.5);      // 512 (square image)
    const int H = P / W;
    const int K = out_size / (B * 32);               // 1024
    const int N = B * K;                             // 16384

    int wlog = -1;
    if ((W & (W - 1)) == 0) { wlog = 0; while ((1 << wlog) < W) ++wlog; }

    const int nblk = (N + 63) / 64;                  // 256 blocks

    int chunks = 32;                                 // 2 co-resident pool blocks/CU
    while (chunks > 1 && (P % (chunks * 4)) != 0) chunks >>= 1;
    while (P / chunks > 16384) chunks <<= 1;         // u64 fxy packing bound (2^14 scale)

    // workspace (floats): statA[nblk*128] | statB[nblk*64]
    //                   | partial[B*chunks*K*5] | h1[64*N] | h2[32*N]
    float* statA   = (float*)d_ws;
    float* statB   = statA + (size_t)nblk * 128;
    float* partial = statB + (size_t)nblk * 64;
    float* h1g     = partial + (size_t)B * chunks * K * 5;
    float* h2g     = h1g + (size_t)64 * N;

    pool_kernel<<<B * chunks, TPBP, (size_t)K * 16, stream>>>(
        labels, fx, fy, partial, K, H, W, wlog, chunks);
    k_layer1<<<nblk, TPB, 0, stream>>>(
        partial, frame_idx, n_frames_p, conv_w, conv_b, statA, h1g, K, N, chunks);
    k_layer2<<<nblk, TPB, 0, stream>>>(
        statA, bn1_g, bn1_b, lin_w, lin_b, h1g, statB, h2g, N);
    k_final<<<nblk, TPB, 0, stream>>>(
        statB, bn2_g, bn2_b, h2g, out, N);
}

// Round 7
// 131.541 us; speedup vs baseline: 1.0301x; 1.0301x over previous
//
#include <hip/hip_runtime.h>
#include <math.h>

#define TPB 256                    // dense-phase kernels block size
#define TPBP 1024                  // pool kernel block size (round-4 proven config)
#define FSCALE 16384.0f            // 2^14 fixed-point for fx/fy
#define INV_FSCALE (1.0f / 16384.0f)
#define FBIAS (1 << 17)            // per-add bias keeps packed fields positive
#define FCLAMP 7.0f                // |fx| clamp: 7*2^14 + 2^17 = 245760; *16384 < 2^32

// Round-6: pool reverted to round-4 (chunks=16, 1024 thr; round-5's 2-block/CU
// split regressed +7us -> pool is LDS-atomic/load pipe bound, leave it).
// Dense chain slimmed via linearity: bn1 stats over h1 = W x + b are exact
// functions of S = sum(x), M = sum(x x^T) (20 floats/block instead of h1
// itself). K2 never computes/stores h1 (saves 4MB W + 4MB R + a stat pass);
// K3 reduces the 20x256 moment table, folds bn1 analytically, recomputes
// h1->y from feat (320 FMA, ONE kernel only - round-2's two-kernel recompute
// was the mistake), then layer2 -> h2g + statB as round-4. K4 unchanged.

// -------------------- pool: LDS int bins, 2 u64 atomics/pixel --------------------
__global__ __launch_bounds__(TPBP)
void pool_kernel(const int* __restrict__ labels,
                 const float* __restrict__ fx,
                 const float* __restrict__ fy,
                 float* __restrict__ partial,
                 int K, int H, int W, int wlog, int chunks) {
    extern __shared__ unsigned long long sh[];   // geo[K] | fxy[K]
    unsigned long long* geo = sh;
    unsigned long long* fxy = sh + K;
    const int tid = threadIdx.x;

    for (int i = tid; i < K; i += TPBP) { geo[i] = 0ull; fxy[i] = 0ull; }
    __syncthreads();

    const int P = H * W;
    const int b = blockIdx.x / chunks;
    const int chunk = blockIdx.x - b * chunks;
    const int chunkP = P / chunks;
    const size_t base = (size_t)b * P + (size_t)chunk * chunkP;
    const int4*   l4p  = (const int4*)(labels + base);
    const float4* fx4p = (const float4*)(fx + base);
    const float4* fy4p = (const float4*)(fy + base);
    const int nvec = chunkP >> 2;

    for (int v = tid; v < nvec; v += TPBP) {
        int4   l4 = l4p[v];
        float4 f4 = fx4p[v];
        float4 g4 = fy4p[v];
        int p0 = chunk * chunkP + (v << 2);
        int   ls[4] = {l4.x, l4.y, l4.z, l4.w};
        float fs[4] = {f4.x, f4.y, f4.z, f4.w};
        float gs[4] = {g4.x, g4.y, g4.z, g4.w};
        #pragma unroll
        for (int s = 0; s < 4; ++s) {
            int p = p0 + s;
            int i, j;
            if (wlog >= 0) { i = p >> wlog; j = p & (W - 1); }
            else           { i = p / W;     j = p - i * W; }
            unsigned long long gadd = ((unsigned long long)i << 40)
                                    | ((unsigned long long)j << 16) | 1ull;
            int qx = __float2int_rn(fminf(fmaxf(fs[s], -FCLAMP), FCLAMP) * FSCALE) + FBIAS;
            int qy = __float2int_rn(fminf(fmaxf(gs[s], -FCLAMP), FCLAMP) * FSCALE) + FBIAS;
            unsigned long long fadd = ((unsigned long long)(unsigned int)qx << 32)
                                    | (unsigned long long)(unsigned int)qy;
            atomicAdd(&geo[ls[s]], gadd);
            atomicAdd(&fxy[ls[s]], fadd);
        }
    }
    __syncthreads();

    const float sx = 2.f / (float)(H - 1);           // xx varies along dim 2 (i)
    const float sy = 2.f / (float)(W - 1);           // yy varies along dim 3 (j)
    float* outp = partial + (size_t)blockIdx.x * K * 5;   // plane-major [f][K]
    for (int k = tid; k < K; k += TPBP) {
        unsigned long long g = geo[k];
        unsigned long long ff = fxy[k];
        unsigned int ci = (unsigned int)(g & 0xFFFFull);
        float cnt = (float)ci;
        float sj  = (float)(unsigned int)((g >> 16) & 0xFFFFFFull);
        float si  = (float)(unsigned int)(g >> 40);
        long long cbias = (long long)ci << 17;
        outp[0 * K + k] = (float)((long long)(ff >> 32) - cbias) * INV_FSCALE;
        outp[1 * K + k] = (float)((long long)(ff & 0xFFFFFFFFull) - cbias) * INV_FSCALE;
        outp[2 * K + k] = sx * si - cnt;             // sum xx
        outp[3 * K + k] = sy * sj - cnt;             // sum yy
        outp[4 * K + k] = cnt;                       // count
    }
}

// Unrolled strided accumulate: ROWS compile-time -> all loads in flight.
template <int ROWS>
__device__ __forceinline__ float red_fixed(const float* __restrict__ base, int stride) {
    float a = 0.f;
    #pragma unroll
    for (int r = 0; r < ROWS; ++r) a += base[(size_t)r * stride];
    return a;
}
__device__ __forceinline__ float red_dyn(const float* __restrict__ base, int rows, int stride) {
    float a = 0.f;
    #pragma unroll 8
    for (int r = 0; r < rows; ++r) a += base[(size_t)r * stride];
    return a;
}

// moment index map: q 0..4 = S_f; q 5..19 = upper-tri pairs of M
__constant__ int PA[15] = {0,0,0,0,0, 1,1,1,1, 2,2,2, 3,3, 4};
__constant__ int PB[15] = {0,1,2,3,4, 1,2,3,4, 2,3,4, 3,4, 4};

// -------------------- K2: slab reduce -> feat[5][N] + x-moment partials ----------
__global__ __launch_bounds__(TPB)
void k_feat(const float* __restrict__ partial,
            const int* __restrict__ frame_idx,
            const int* __restrict__ n_frames_p,
            float* __restrict__ statM,   // [nblk][32]: 5 S | 15 M(upper-tri) | pad
            float* __restrict__ featg,   // [5][N]
            int K, int N, int chunks) {
    __shared__ float red[320];                       // [f][64]
    __shared__ float xls[5 * 65];                    // [f][tt], padded
    __shared__ float pm[8 * 32];

    const int tid = threadIdx.x;
    const int bid = blockIdx.x;

    const int t0 = bid * 64;
    const int b  = t0 / K;                           // 64 | K -> one batch per block
    const int k0 = t0 - b * K;

    // plane-major reads: wave f1 reads plane f1, fully coalesced
    const int f1 = tid >> 6, kk = tid & 63;
    float a0 = 0.f, a1 = 0.f;
    const float* pb = partial + (size_t)b * chunks * K * 5;
    if (chunks == 16) {
        #pragma unroll
        for (int ch = 0; ch < 16; ++ch) {
            const float* pc = pb + (size_t)ch * K * 5;
            a0 += pc[(size_t)f1 * K + k0 + kk];
            if (tid < 64) a1 += pc[(size_t)4 * K + k0 + tid];
        }
    } else {
        #pragma unroll 4
        for (int ch = 0; ch < chunks; ++ch) {
            const float* pc = pb + (size_t)ch * K * 5;
            a0 += pc[(size_t)f1 * K + k0 + kk];
            if (tid < 64) a1 += pc[(size_t)4 * K + k0 + tid];
        }
    }
    red[f1 * 64 + kk] = a0;
    if (tid < 64) red[4 * 64 + tid] = a1;
    __syncthreads();

    const int g  = tid >> 6;
    const int tt = tid & 63;
    const int t  = t0 + tt;
    const bool valid = t < N;

    if (g == 0) {
        const float cntv = red[4 * 64 + tt];
        const float inv  = 1.f / fmaxf(cntv, 1.f);
        const float invnf = 1.f / (float)(n_frames_p[0] - 1);
        const float x0 = valid ? (float)frame_idx[b] * invnf : 0.f;
        const float x1 = red[0 * 64 + tt] * inv;
        const float x2 = red[1 * 64 + tt] * inv;
        const float x3 = red[2 * 64 + tt] * inv;
        const float x4 = red[3 * 64 + tt] * inv;
        if (valid) {                                 // coalesced plane stores
            featg[(size_t)0 * N + t] = x0;
            featg[(size_t)1 * N + t] = x1;
            featg[(size_t)2 * N + t] = x2;
            featg[(size_t)3 * N + t] = x3;
            featg[(size_t)4 * N + t] = x4;
        }
        xls[0 * 65 + tt] = valid ? x0 : 0.f;         // masked for moments
        xls[1 * 65 + tt] = valid ? x1 : 0.f;
        xls[2 * 65 + tt] = valid ? x2 : 0.f;
        xls[3 * 65 + tt] = valid ? x3 : 0.f;
        xls[4 * 65 + tt] = valid ? x4 : 0.f;
    }
    __syncthreads();

    // moment partials: quantity q over this block's 64 tokens
    {
        const int q = tid & 31, rr = tid >> 5;       // rr = 0..7, 8 tokens each
        float s = 0.f;
        if (q < 5) {
            #pragma unroll
            for (int i = 0; i < 8; ++i) s += xls[q * 65 + rr * 8 + i];
        } else if (q < 20) {
            const int a = PA[q - 5], c = PB[q - 5];
            #pragma unroll
            for (int i = 0; i < 8; ++i) {
                int tok = rr * 8 + i;
                s += xls[a * 65 + tok] * xls[c * 65 + tok];
            }
        }
        pm[rr * 32 + q] = s;
    }
    __syncthreads();
    if (tid < 20) {
        float s = 0.f;
        #pragma unroll
        for (int grp = 0; grp < 8; ++grp) s += pm[grp * 32 + tid];
        statM[(size_t)bid * 32 + tid] = s;           // plain stores: zero contention
    }
}

// -------------------- K3: moment reduce -> analytic bn1 + layer2 -> h2g + statB --
__global__ __launch_bounds__(TPB)
void k_layer2(const float* __restrict__ statM,
              const float* __restrict__ bn1_g,
              const float* __restrict__ bn1_b,
              const float* __restrict__ conv_w,
              const float* __restrict__ conv_b,
              const float* __restrict__ lin_w,
              const float* __restrict__ lin_b,
              const float* __restrict__ featg,  // [5][N]
              float* __restrict__ statB,        // [nblk][64]: 32 sum | 32 sumsq
              float* __restrict__ h2g,          // [32][N]
              int N) {
    __shared__ float pm[8 * 32], SM[20];
    __shared__ float cw[320], cb[64], w2[2048], lb[32];
    __shared__ float sc1[64], sh1[64];
    __shared__ float h2t[32 * 65];                   // [o][tt], pad 65 for col reads
    __shared__ float ps[256], pq[256];

    const int tid = threadIdx.x;
    const int bid = blockIdx.x;
    const int nblk = gridDim.x;
    const int t0 = bid * 64;

    for (int i = tid; i < 320; i += TPB) cw[i] = conv_w[i];
    if (tid < 64) cb[tid] = conv_b[tid];
    for (int i = tid; i < 2048; i += TPB) w2[i] = lin_w[i];
    if (tid < 32) lb[tid] = lin_b[tid];

    // redundant moment reduce: tiny (20 cols x nblk rows), all loads in flight
    {
        const int q = tid & 31, grp = tid >> 5;      // 8 groups
        float a = 0.f;
        if (q < 20) {
            const int rows = nblk >> 3;
            const float* base = statM + (size_t)grp * rows * 32 + q;
            a = (rows == 32) ? red_fixed<32>(base, 32) : red_dyn(base, rows, 32);
        }
        pm[grp * 32 + q] = a;
    }

    const int g  = tid >> 6;
    const int tt = tid & 63;
    const int t  = t0 + tt;
    const bool valid = t < N;

    // feature loads (coalesced plane reads) overlap the reduce tail
    const float x0 = featg[(size_t)0 * N + t];
    const float x1 = featg[(size_t)1 * N + t];
    const float x2 = featg[(size_t)2 * N + t];
    const float x3 = featg[(size_t)3 * N + t];
    const float x4 = featg[(size_t)4 * N + t];
    __syncthreads();

    if (tid < 20) {
        float s = 0.f;
        #pragma unroll
        for (int grp = 0; grp < 8; ++grp) s += pm[grp * 32 + tid];
        SM[tid] = s;
    }
    __syncthreads();

    if (tid < 64) {
        // analytic bn1 stats: sum = N b + w.S ; sumsq = N b^2 + 2b(w.S) + w M w^T
        const int idx[5][5] = {{5,6,7,8,9},{6,10,11,12,13},{7,11,14,15,16},
                               {8,12,15,17,18},{9,13,16,18,19}};
        float w[5];
        #pragma unroll
        for (int f = 0; f < 5; ++f) w[f] = cw[tid * 5 + f];
        float wS = 0.f;
        #pragma unroll
        for (int f = 0; f < 5; ++f) wS += w[f] * SM[f];
        float quad = 0.f;
        #pragma unroll
        for (int f = 0; f < 5; ++f) {
            float r = 0.f;
            #pragma unroll
            for (int gg = 0; gg < 5; ++gg) r += w[gg] * SM[idx[f][gg]];
            quad += w[f] * r;
        }
        const float cbv = cb[tid];
        const float fN = (float)N;
        float su = fN * cbv + wS;
        float sq = fN * cbv * cbv + 2.f * cbv * wS + quad;
        float invN = 1.f / fN;
        float mean = su * invN;
        float var  = sq * invN - mean * mean;
        float s = bn1_g[tid] * rsqrtf(var + 1e-5f);
        sc1[tid] = s;
        sh1[tid] = bn1_b[tid] - mean * s;
    }
    __syncthreads();

    // recompute h1 -> y from feat (registers only; ONE kernel's recompute)
    float y[64];
    #pragma unroll
    for (int c = 0; c < 64; ++c) {
        const float* w = cw + c * 5;
        float h = cb[c] + w[0]*x0 + w[1]*x1 + w[2]*x2 + w[3]*x3 + w[4]*x4;
        y[c] = fmaxf(h * sc1[c] + sh1[c], 0.f);
    }

    const int o0 = g * 8;
    #pragma unroll
    for (int j = 0; j < 8; ++j) {
        int o = o0 + j;
        const float* wo = w2 + o * 64;
        float acc = lb[o];
        #pragma unroll
        for (int c = 0; c < 64; ++c) acc += wo[c] * y[c];
        if (valid) h2g[(size_t)o * N + t] = acc;     // lane-coalesced dword store
        h2t[o * 65 + tt] = valid ? acc : 0.f;        // masked copy for stats
    }
    __syncthreads();

    // transpose stat reduce: thread (o, rr) sums 8 tokens of channel o
    {
        const int o = tid & 31, rr = tid >> 5;       // rr = 0..7
        float s = 0.f, q = 0.f;
        #pragma unroll
        for (int i = 0; i < 8; ++i) {                // bank = (o+8rr+i)%32: free
            float v = h2t[o * 65 + rr * 8 + i];
            s += v; q += v * v;
        }
        ps[rr * 32 + o] = s;
        pq[rr * 32 + o] = q;
    }
    __syncthreads();
    if (tid < 32) {
        float su = 0.f, sq = 0.f;
        #pragma unroll
        for (int rr = 0; rr < 8; ++rr) { su += ps[rr * 32 + tid]; sq += pq[rr * 32 + tid]; }
        statB[(size_t)bid * 64 + tid] = su;
        statB[(size_t)bid * 64 + 32 + tid] = sq;
    }
}

// -------------------- K4: statB reduce -> bn2 fold + normalize + store -----------
__global__ __launch_bounds__(TPB)
void k_final(const float* __restrict__ statB,
             const float* __restrict__ bn2_g,
             const float* __restrict__ bn2_b,
             const float* __restrict__ h2g,     // [32][N]
             float* __restrict__ out,
             int N) {
    __shared__ float red[256];
    __shared__ float sc2[32], sh2[32];
    __shared__ float h2t[32 * 68];                   // [o][tt], 16B-aligned rows
    __shared__ float ssqp[4 * 64], linv[64];

    const int tid = threadIdx.x;
    const int bid = blockIdx.x;
    const int nblk = gridDim.x;
    const int t0 = bid * 64;

    // redundant statB reduce: compile-time trip count
    {
        const int col = tid & 63;                    // 0..31 sums, 32..63 sumsq
        const int qr  = tid >> 6;
        const int rows = nblk >> 2;
        const float* base = statB + (size_t)qr * rows * 64 + col;
        red[tid] = (rows == 64) ? red_fixed<64>(base, 64)
                                : red_dyn(base, rows, 64);
    }

    // stage h2 tile [32o][64t] -> LDS
    {
        #pragma unroll
        for (int pass = 0; pass < 2; ++pass) {
            int idx = pass * TPB + tid;              // 0..511 float4s
            int o = idx >> 4, q = idx & 15;
            float4 v = *(const float4*)(h2g + (size_t)o * N + t0 + q * 4);
            *(float4*)(&h2t[o * 68 + q * 4]) = v;
        }
    }
    __syncthreads();

    if (tid < 32) {
        float su = red[tid] + red[64 + tid] + red[128 + tid] + red[192 + tid];
        float sq = red[32 + tid] + red[96 + tid] + red[160 + tid] + red[224 + tid];
        float invN = 1.f / (float)N;
        float mean = su * invN;
        float var  = sq * invN - mean * mean;
        float s = bn2_g[tid] * rsqrtf(var + 1e-5f);
        sc2[tid] = s;
        sh2[tid] = bn2_b[tid] - mean * s;
    }
    __syncthreads();

    const int g  = tid >> 6;
    const int tt = tid & 63;
    {
        const int o0 = g * 8;
        float ss = 0.f;
        #pragma unroll
        for (int j = 0; j < 8; ++j) {
            int o = o0 + j;
            float v = fmaxf(h2t[o * 68 + tt] * sc2[o] + sh2[o], 0.f);
            h2t[o * 68 + tt] = v;
            ss += v * v;
        }
        ssqp[g * 64 + tt] = ss;
    }
    __syncthreads();
    if (g == 0) {
        float tot = ssqp[tt] + ssqp[64 + tt] + ssqp[128 + tt] + ssqp[192 + tt];
        linv[tt] = 1.f / fmaxf(sqrtf(tot), 1e-8f);
    }
    __syncthreads();

    const int nq = min(512, (N - t0) * 8);           // float4s this block owns
    float4* o4 = (float4*)(out + (size_t)t0 * 32);
    for (int q = tid; q < nq; q += TPB) {
        int tk = q >> 3;
        int oo = (q & 7) * 4;
        float iv = linv[tk];
        o4[q] = make_float4(h2t[(oo + 0) * 68 + tk] * iv,
                            h2t[(oo + 1) * 68 + tk] * iv,
                            h2t[(oo + 2) * 68 + tk] * iv,
                            h2t[(oo + 3) * 68 + tk] * iv);
    }
}

extern "C" void kernel_launch(void* const* d_in, const int* in_sizes, int n_in,
                              void* d_out, int out_size, void* d_ws, size_t ws_size,
                              hipStream_t stream) {
    const int*   labels     = (const int*)d_in[0];
    const float* fx         = (const float*)d_in[1];
    const float* fy         = (const float*)d_in[2];
    const int*   frame_idx  = (const int*)d_in[3];
    const int*   n_frames_p = (const int*)d_in[4];
    // d_in[5] = n_labels (derived from out_size instead)
    const float* conv_w = (const float*)d_in[6];
    const float* conv_b = (const float*)d_in[7];
    const float* bn1_g  = (const float*)d_in[8];
    const float* bn1_b  = (const float*)d_in[9];
    const float* lin_w  = (const float*)d_in[10];
    const float* lin_b  = (const float*)d_in[11];
    const float* bn2_g  = (const float*)d_in[12];
    const float* bn2_b  = (const float*)d_in[13];
    float* out = (float*)d_out;

    const int B = in_sizes[3];                       // 16
    const int P = in_sizes[0] / B;                   // 262144
    const int W = (int)(sqrt((double)P) + 0.5);      // 512 (square image)
    const int H = P / W;
    const int K = out_size / (B * 32);               // 1024
    const int N = B * K;                             // 16384

    int wlog = -1;
    if ((W & (W - 1)) == 0) { wlog = 0; while ((1 << wlog) < W) ++wlog; }

    const int nblk = (N + 63) / 64;                  // 256 blocks

    int chunks = 16;                                 // round-4 proven pool config
    while (chunks > 1 && (P % (chunks * 4)) != 0) chunks >>= 1;
    while (P / chunks > 16384) chunks <<= 1;         // u64 fxy packing bound (2^14 scale)

    // workspace (floats): statM[nblk*32] | statB[nblk*64]
    //                   | partial[B*chunks*K*5] | featg[5*N] | h2[32*N]
    float* statM   = (float*)d_ws;
    float* statB   = statM + (size_t)nblk * 32;
    float* partial = statB + (size_t)nblk * 64;
    float* featg   = partial + (size_t)B * chunks * K * 5;
    float* h2g     = featg + (size_t)5 * N;

    pool_kernel<<<B * chunks, TPBP, (size_t)K * 16, stream>>>(
        labels, fx, fy, partial, K, H, W, wlog, chunks);
    k_feat<<<nblk, TPB, 0, stream>>>(
        partial, frame_idx, n_frames_p, statM, featg, K, N, chunks);
    k_layer2<<<nblk, TPB, 0, stream>>>(
        statM, bn1_g, bn1_b, conv_w, conv_b, lin_w, lin_b, featg,
        statB, h2g, N);
    k_final<<<nblk, TPB, 0, stream>>>(
        statB, bn2_g, bn2_b, h2g, out, N);
}

// Round 8
// 127.109 us; speedup vs baseline: 1.0660x; 1.0349x over previous
//
#include <hip/hip_runtime.h>
#include <math.h>

#define TPB 256                    // dense-phase kernels block size
#define TPBP 1024                  // pool kernel block size
#define FSCALE 16384.0f            // 2^14 fixed-point for fx/fy
#define INV_FSCALE (1.0f / 16384.0f)
#define FBIAS (1 << 17)            // per-add bias keeps packed fields positive
#define FCLAMP 7.0f                // |fx| clamp: 7*2^14 + 2^17 = 245760; *16384 < 2^32

// Round-7: revert to the round-4 structure verbatim (measured best, 128.6us).
// A/B ledger: grid-barriers->splits -19us; h1/h2 recompute +6/+3us; pool
// 2-block/CU +7us; bn1 moment-analytics +3us. Dense kernels are latency/launch
// bound (traffic trims don't help); pool is LDS-atomic/load bound at its
// proven config (chunks=16, 1024 thr). This locks in the best-known kernel.

// -------------------- pool: LDS int bins, 2 u64 atomics/pixel --------------------
__global__ __launch_bounds__(TPBP)
void pool_kernel(const int* __restrict__ labels,
                 const float* __restrict__ fx,
                 const float* __restrict__ fy,
                 float* __restrict__ partial,
                 int K, int H, int W, int wlog, int chunks) {
    extern __shared__ unsigned long long sh[];   // geo[K] | fxy[K]
    unsigned long long* geo = sh;
    unsigned long long* fxy = sh + K;
    const int tid = threadIdx.x;

    for (int i = tid; i < K; i += TPBP) { geo[i] = 0ull; fxy[i] = 0ull; }
    __syncthreads();

    const int P = H * W;
    const int b = blockIdx.x / chunks;
    const int chunk = blockIdx.x - b * chunks;
    const int chunkP = P / chunks;
    const size_t base = (size_t)b * P + (size_t)chunk * chunkP;
    const int4*   l4p  = (const int4*)(labels + base);
    const float4* fx4p = (const float4*)(fx + base);
    const float4* fy4p = (const float4*)(fy + base);
    const int nvec = chunkP >> 2;

    for (int v = tid; v < nvec; v += TPBP) {
        int4   l4 = l4p[v];
        float4 f4 = fx4p[v];
        float4 g4 = fy4p[v];
        int p0 = chunk * chunkP + (v << 2);
        int   ls[4] = {l4.x, l4.y, l4.z, l4.w};
        float fs[4] = {f4.x, f4.y, f4.z, f4.w};
        float gs[4] = {g4.x, g4.y, g4.z, g4.w};
        #pragma unroll
        for (int s = 0; s < 4; ++s) {
            int p = p0 + s;
            int i, j;
            if (wlog >= 0) { i = p >> wlog; j = p & (W - 1); }
            else           { i = p / W;     j = p - i * W; }
            unsigned long long gadd = ((unsigned long long)i << 40)
                                    | ((unsigned long long)j << 16) | 1ull;
            int qx = __float2int_rn(fminf(fmaxf(fs[s], -FCLAMP), FCLAMP) * FSCALE) + FBIAS;
            int qy = __float2int_rn(fminf(fmaxf(gs[s], -FCLAMP), FCLAMP) * FSCALE) + FBIAS;
            unsigned long long fadd = ((unsigned long long)(unsigned int)qx << 32)
                                    | (unsigned long long)(unsigned int)qy;
            atomicAdd(&geo[ls[s]], gadd);
            atomicAdd(&fxy[ls[s]], fadd);
        }
    }
    __syncthreads();

    const float sx = 2.f / (float)(H - 1);           // xx varies along dim 2 (i)
    const float sy = 2.f / (float)(W - 1);           // yy varies along dim 3 (j)
    float* outp = partial + (size_t)blockIdx.x * K * 5;   // plane-major [f][K]
    for (int k = tid; k < K; k += TPBP) {
        unsigned long long g = geo[k];
        unsigned long long ff = fxy[k];
        unsigned int ci = (unsigned int)(g & 0xFFFFull);
        float cnt = (float)ci;
        float sj  = (float)(unsigned int)((g >> 16) & 0xFFFFFFull);
        float si  = (float)(unsigned int)(g >> 40);
        long long cbias = (long long)ci << 17;
        outp[0 * K + k] = (float)((long long)(ff >> 32) - cbias) * INV_FSCALE;
        outp[1 * K + k] = (float)((long long)(ff & 0xFFFFFFFFull) - cbias) * INV_FSCALE;
        outp[2 * K + k] = sx * si - cnt;             // sum xx
        outp[3 * K + k] = sy * sj - cnt;             // sum yy
        outp[4 * K + k] = cnt;                       // count
    }
}

// Unrolled strided accumulate: ROWS compile-time -> all loads in flight.
template <int ROWS>
__device__ __forceinline__ float red_fixed(const float* __restrict__ base, int stride) {
    float a = 0.f;
    #pragma unroll
    for (int r = 0; r < ROWS; ++r) a += base[(size_t)r * stride];
    return a;
}
__device__ __forceinline__ float red_dyn(const float* __restrict__ base, int rows, int stride) {
    float a = 0.f;
    #pragma unroll 8
    for (int r = 0; r < rows; ++r) a += base[(size_t)r * stride];
    return a;
}

// -------------------- K2: slab reduce -> feat + layer1 -> h1g + bn1 partials -----
__global__ __launch_bounds__(TPB)
void k_layer1(const float* __restrict__ partial,
              const int* __restrict__ frame_idx,
              const int* __restrict__ n_frames_p,
              const float* __restrict__ conv_w,
              const float* __restrict__ conv_b,
              float* __restrict__ statA,   // [nblk][128]: 64 sum | 64 sumsq
              float* __restrict__ h1g,     // [64][N]
              int K, int N, int chunks) {
    __shared__ float red[320];                       // [f][64]
    __shared__ float cw[320], cb[64];
    __shared__ float h1t[64 * 65];                   // [c][tt], pad 65 for col reads
    __shared__ float ps[256], pq[256];

    const int tid = threadIdx.x;
    const int bid = blockIdx.x;

    for (int i = tid; i < 320; i += TPB) cw[i] = conv_w[i];
    if (tid < 64) cb[tid] = conv_b[tid];

    const int t0 = bid * 64;
    const int b  = t0 / K;                           // 64 | K -> one batch per block
    const int k0 = t0 - b * K;

    // plane-major reads: wave f1 reads plane f1, fully coalesced
    const int f1 = tid >> 6, kk = tid & 63;
    float a0 = 0.f, a1 = 0.f;
    const float* pb = partial + (size_t)b * chunks * K * 5;
    if (chunks == 16) {
        #pragma unroll
        for (int ch = 0; ch < 16; ++ch) {
            const float* pc = pb + (size_t)ch * K * 5;
            a0 += pc[(size_t)f1 * K + k0 + kk];
            if (tid < 64) a1 += pc[(size_t)4 * K + k0 + tid];
        }
    } else {
        #pragma unroll 4
        for (int ch = 0; ch < chunks; ++ch) {
            const float* pc = pb + (size_t)ch * K * 5;
            a0 += pc[(size_t)f1 * K + k0 + kk];
            if (tid < 64) a1 += pc[(size_t)4 * K + k0 + tid];
        }
    }
    red[f1 * 64 + kk] = a0;
    if (tid < 64) red[4 * 64 + tid] = a1;
    __syncthreads();

    const int g  = tid >> 6;
    const int tt = tid & 63;
    const int t  = t0 + tt;
    const bool valid = t < N;

    const float cntv = red[4 * 64 + tt];
    const float inv  = 1.f / fmaxf(cntv, 1.f);
    const float invnf = 1.f / (float)(n_frames_p[0] - 1);
    const float x0 = valid ? (float)frame_idx[b] * invnf : 0.f;
    const float x1 = red[0 * 64 + tt] * inv;
    const float x2 = red[1 * 64 + tt] * inv;
    const float x3 = red[2 * 64 + tt] * inv;
    const float x4 = red[3 * 64 + tt] * inv;

    const int c0 = g * 16;
    #pragma unroll
    for (int j = 0; j < 16; ++j) {
        int c = c0 + j;
        const float* w = cw + c * 5;
        float h = cb[c] + w[0]*x0 + w[1]*x1 + w[2]*x2 + w[3]*x3 + w[4]*x4;
        h1g[(size_t)c * N + t] = h;                  // lane-coalesced dword store
        h1t[c * 65 + tt] = valid ? h : 0.f;          // masked copy for stats
    }
    __syncthreads();

    // transpose stat reduce: thread (cc, rr) sums 16 tokens of channel cc
    {
        const int cc = tid & 63, rr = tid >> 6;      // rr = 0..3
        float s = 0.f, q = 0.f;
        #pragma unroll
        for (int i = 0; i < 16; ++i) {               // bank = (cc+16rr+i)%32: free
            float v = h1t[cc * 65 + rr * 16 + i];
            s += v; q += v * v;
        }
        ps[rr * 64 + cc] = s;
        pq[rr * 64 + cc] = q;
    }
    __syncthreads();
    if (tid < 64) {
        float su = ps[tid] + ps[64 + tid] + ps[128 + tid] + ps[192 + tid];
        float sq = pq[tid] + pq[64 + tid] + pq[128 + tid] + pq[192 + tid];
        statA[(size_t)bid * 128 + tid] = su;         // plain stores: zero contention
        statA[(size_t)bid * 128 + 64 + tid] = sq;
    }
}

// -------------------- K3: statA reduce -> bn1 fold + layer2 -> h2g + bn2 partials
__global__ __launch_bounds__(TPB)
void k_layer2(const float* __restrict__ statA,
              const float* __restrict__ bn1_g,
              const float* __restrict__ bn1_b,
              const float* __restrict__ lin_w,
              const float* __restrict__ lin_b,
              const float* __restrict__ h1g,    // [64][N]
              float* __restrict__ statB,        // [nblk][64]: 32 sum | 32 sumsq
              float* __restrict__ h2g,          // [32][N]
              int N) {
    __shared__ float red[256], w2[2048], lb[32];
    __shared__ float sc1[64], sh1[64];
    __shared__ float h1t[64 * 64];                   // [c][tt] staged tile
    __shared__ float h2t[32 * 65];                   // [o][tt], pad 65 for col reads
    __shared__ float ps[256], pq[256];

    const int tid = threadIdx.x;
    const int bid = blockIdx.x;
    const int nblk = gridDim.x;
    const int t0 = bid * 64;

    for (int i = tid; i < 2048; i += TPB) w2[i] = lin_w[i];
    if (tid < 32) lb[tid] = lin_b[tid];

    // redundant statA reduce: compile-time trip count, all loads in flight
    {
        const int col  = tid & 127;                  // 0..63 sums, 64..127 sumsq
        const int half = tid >> 7;
        const int rows = nblk >> 1;
        const float* base = statA + (size_t)half * rows * 128 + col;
        red[tid] = (rows == 128) ? red_fixed<128>(base, 128)
                                 : red_dyn(base, rows, 128);
    }

    // stage h1 tile [64c][64t] -> LDS (overlaps the reduce's tail)
    {
        #pragma unroll
        for (int pass = 0; pass < 4; ++pass) {
            int idx = pass * TPB + tid;              // 0..1023 float4s
            int c = idx >> 4, q = idx & 15;
            float4 v = *(const float4*)(h1g + (size_t)c * N + t0 + q * 4);
            *(float4*)(&h1t[c * 64 + q * 4]) = v;
        }
    }
    __syncthreads();

    if (tid < 64) {
        float su = red[tid] + red[128 + tid];
        float sq = red[64 + tid] + red[192 + tid];
        float invN = 1.f / (float)N;
        float mean = su * invN;
        float var  = sq * invN - mean * mean;
        float s = bn1_g[tid] * rsqrtf(var + 1e-5f);
        sc1[tid] = s;
        sh1[tid] = bn1_b[tid] - mean * s;
    }
    __syncthreads();

    const int g  = tid >> 6;
    const int tt = tid & 63;
    const int t  = t0 + tt;
    const bool valid = t < N;

    float y[64];
    #pragma unroll
    for (int c = 0; c < 64; ++c)
        y[c] = fmaxf(h1t[c * 64 + tt] * sc1[c] + sh1[c], 0.f);

    const int o0 = g * 8;
    #pragma unroll
    for (int j = 0; j < 8; ++j) {
        int o = o0 + j;
        const float* wo = w2 + o * 64;
        float acc = lb[o];
        #pragma unroll
        for (int c = 0; c < 64; ++c) acc += wo[c] * y[c];
        h2g[(size_t)o * N + t] = acc;                // lane-coalesced dword store
        h2t[o * 65 + tt] = valid ? acc : 0.f;        // masked copy for stats
    }
    __syncthreads();

    // transpose stat reduce: thread (o, rr) sums 8 tokens of channel o
    {
        const int o = tid & 31, rr = tid >> 5;       // rr = 0..7
        float s = 0.f, q = 0.f;
        #pragma unroll
        for (int i = 0; i < 8; ++i) {                // bank = (o+8rr+i)%32: free
            float v = h2t[o * 65 + rr * 8 + i];
            s += v; q += v * v;
        }
        ps[rr * 32 + o] = s;
        pq[rr * 32 + o] = q;
    }
    __syncthreads();
    if (tid < 32) {
        float su = 0.f, sq = 0.f;
        #pragma unroll
        for (int rr = 0; rr < 8; ++rr) { su += ps[rr * 32 + tid]; sq += pq[rr * 32 + tid]; }
        statB[(size_t)bid * 64 + tid] = su;
        statB[(size_t)bid * 64 + 32 + tid] = sq;
    }
}

// -------------------- K4: statB reduce -> bn2 fold + normalize + store -----------
__global__ __launch_bounds__(TPB)
void k_final(const float* __restrict__ statB,
             const float* __restrict__ bn2_g,
             const float* __restrict__ bn2_b,
             const float* __restrict__ h2g,     // [32][N]
             float* __restrict__ out,
             int N) {
    __shared__ float red[256];
    __shared__ float sc2[32], sh2[32];
    __shared__ float h2t[32 * 68];                   // [o][tt], 16B-aligned rows
    __shared__ float ssqp[4 * 64], linv[64];

    const int tid = threadIdx.x;
    const int bid = blockIdx.x;
    const int nblk = gridDim.x;
    const int t0 = bid * 64;

    // redundant statB reduce: compile-time trip count
    {
        const int col = tid & 63;                    // 0..31 sums, 32..63 sumsq
        const int qr  = tid >> 6;
        const int rows = nblk >> 2;
        const float* base = statB + (size_t)qr * rows * 64 + col;
        red[tid] = (rows == 64) ? red_fixed<64>(base, 64)
                                : red_dyn(base, rows, 64);
    }

    // stage h2 tile [32o][64t] -> LDS
    {
        #pragma unroll
        for (int pass = 0; pass < 2; ++pass) {
            int idx = pass * TPB + tid;              // 0..511 float4s
            int o = idx >> 4, q = idx & 15;
            float4 v = *(const float4*)(h2g + (size_t)o * N + t0 + q * 4);
            *(float4*)(&h2t[o * 68 + q * 4]) = v;
        }
    }
    __syncthreads();

    if (tid < 32) {
        float su = red[tid] + red[64 + tid] + red[128 + tid] + red[192 + tid];
        float sq = red[32 + tid] + red[96 + tid] + red[160 + tid] + red[224 + tid];
        float invN = 1.f / (float)N;
        float mean = su * invN;
        float var  = sq * invN - mean * mean;
        float s = bn2_g[tid] * rsqrtf(var + 1e-5f);
        sc2[tid] = s;
        sh2[tid] = bn2_b[tid] - mean * s;
    }
    __syncthreads();

    const int g  = tid >> 6;
    const int tt = tid & 63;
    {
        const int o0 = g * 8;
        float ss = 0.f;
        #pragma unroll
        for (int j = 0; j < 8; ++j) {
            int o = o0 + j;
            float v = fmaxf(h2t[o * 68 + tt] * sc2[o] + sh2[o], 0.f);
            h2t[o * 68 + tt] = v;
            ss += v * v;
        }
        ssqp[g * 64 + tt] = ss;
    }
    __syncthreads();
    if (g == 0) {
        float tot = ssqp[tt] + ssqp[64 + tt] + ssqp[128 + tt] + ssqp[192 + tt];
        linv[tt] = 1.f / fmaxf(sqrtf(tot), 1e-8f);
    }
    __syncthreads();

    const int nq = min(512, (N - t0) * 8);           // float4s this block owns
    float4* o4 = (float4*)(out + (size_t)t0 * 32);
    for (int q = tid; q < nq; q += TPB) {
        int tk = q >> 3;
        int oo = (q & 7) * 4;
        float iv = linv[tk];
        o4[q] = make_float4(h2t[(oo + 0) * 68 + tk] * iv,
                            h2t[(oo + 1) * 68 + tk] * iv,
                            h2t[(oo + 2) * 68 + tk] * iv,
                            h2t[(oo + 3) * 68 + tk] * iv);
    }
}

extern "C" void kernel_launch(void* const* d_in, const int* in_sizes, int n_in,
                              void* d_out, int out_size, void* d_ws, size_t ws_size,
                              hipStream_t stream) {
    const int*   labels     = (const int*)d_in[0];
    const float* fx         = (const float*)d_in[1];
    const float* fy         = (const float*)d_in[2];
    const int*   frame_idx  = (const int*)d_in[3];
    const int*   n_frames_p = (const int*)d_in[4];
    // d_in[5] = n_labels (derived from out_size instead)
    const float* conv_w = (const float*)d_in[6];
    const float* conv_b = (const float*)d_in[7];
    const float* bn1_g  = (const float*)d_in[8];
    const float* bn1_b  = (const float*)d_in[9];
    const float* lin_w  = (const float*)d_in[10];
    const float* lin_b  = (const float*)d_in[11];
    const float* bn2_g  = (const float*)d_in[12];
    const float* bn2_b  = (const float*)d_in[13];
    float* out = (float*)d_out;

    const int B = in_sizes[3];                       // 16
    const int P = in_sizes[0] / B;                   // 262144
    const int W = (int)(sqrt((double)P) + 0.5);      // 512 (square image)
    const int H = P / W;
    const int K = out_size / (B * 32);               // 1024
    const int N = B * K;                             // 16384

    int wlog = -1;
    if ((W & (W - 1)) == 0) { wlog = 0; while ((1 << wlog) < W) ++wlog; }

    const int nblk = (N + 63) / 64;                  // 256 blocks

    int chunks = 16;
    while (chunks > 1 && (P % (chunks * 4)) != 0) chunks >>= 1;
    while (P / chunks > 16384) chunks <<= 1;         // u64 fxy packing bound (2^14 scale)

    // workspace (floats): statA[nblk*128] | statB[nblk*64]
    //                   | partial[B*chunks*K*5] | h1[64*N] | h2[32*N]
    float* statA   = (float*)d_ws;
    float* statB   = statA + (size_t)nblk * 128;
    float* partial = statB + (size_t)nblk * 64;
    float* h1g     = partial + (size_t)B * chunks * K * 5;
    float* h2g     = h1g + (size_t)64 * N;

    pool_kernel<<<B * chunks, TPBP, (size_t)K * 16, stream>>>(
        labels, fx, fy, partial, K, H, W, wlog, chunks);
    k_layer1<<<nblk, TPB, 0, stream>>>(
        partial, frame_idx, n_frames_p, conv_w, conv_b, statA, h1g, K, N, chunks);
    k_layer2<<<nblk, TPB, 0, stream>>>(
        statA, bn1_g, bn1_b, lin_w, lin_b, h1g, statB, h2g, N);
    k_final<<<nblk, TPB, 0, stream>>>(
        statB, bn2_g, bn2_b, h2g, out, N);
}